// Round 16
// baseline (78.207 us; speedup 1.0000x reference)
//
#include <hip/hip_runtime.h>
#include <hip/hip_bf16.h>

typedef short bf16x8 __attribute__((ext_vector_type(8)));
typedef float f32x4  __attribute__((ext_vector_type(4)));
typedef int   i32x4  __attribute__((ext_vector_type(4)));

#define T_AUDIO 262144
#define PADL 384
#define CUTOFF 513
#define CPAD 576       // layout: p=c for c<=256, hole 257..263, p=c+7 for c>=257, tail 520..575 zero
#define NMELS 80
#define PCH 16448      // chunks per global plane (per b, per parity)
#define PBYTES (PCH*16)
#define EB64 17152     // bytes per parity plane in LDS (1072 chunks, 64-frame segment)

__device__ __forceinline__ unsigned short f2bf(float f){
  union { float f; unsigned u; } v; v.f = f;
  return (unsigned short)((v.u + 0x7FFFu + ((v.u >> 16) & 1u)) >> 16);
}
__device__ __forceinline__ float bf2f(unsigned short u){
  union { unsigned u; float f; } v; v.u = (unsigned)u << 16; return v.f;
}

__device__ __forceinline__ void gload_lds16(const void* g, void* l){
  __builtin_amdgcn_global_load_lds(
      (const __attribute__((address_space(1))) unsigned int*)g,
      (__attribute__((address_space(3))) unsigned int*)l, 16, 0, 0);
}

// ---------- k_audio: reflect-padded bf16 E/O planes, natural layout ----------
__global__ void k_audio(const float* __restrict__ audio, unsigned short* __restrict__ planes){
  int bx = blockIdx.x;              // 2080 blocks = 32 b x 65
  int b  = bx / 65;
  int ci = (bx % 65) * 256 + threadIdx.x;
  if (ci >= PCH) return;
  const float* ap = audio + (long)b * T_AUDIO;
  int s0 = 16 * ci - 384;
  float v[16];
  if (s0 >= 0 && s0 + 15 < T_AUDIO){
    #pragma unroll
    for (int q = 0; q < 4; ++q){
      f32x4 a = *(const f32x4*)(ap + s0 + q * 4);
      v[q*4]=a[0]; v[q*4+1]=a[1]; v[q*4+2]=a[2]; v[q*4+3]=a[3];
    }
  } else {
    #pragma unroll
    for (int e = 0; e < 16; ++e){
      int s = s0 + e;
      if (s < 0) s = -s;
      if (s >= T_AUDIO) s = 2*(T_AUDIO-1) - s;
      v[e] = ap[s];
    }
  }
  bf16x8 ev, ov;
  #pragma unroll
  for (int e = 0; e < 8; ++e){
    ev[e] = (short)f2bf(v[2*e]);
    ov[e] = (short)f2bf(v[2*e+1]);
  }
  unsigned short* pE = planes + (long)b * 2 * (PCH * 8);
  *(bf16x8*)(pE + (long)ci * 8)            = ev;
  *(bf16x8*)(pE + PCH * 8 + (long)ci * 8)  = ov;
}

// ---------- k_prep: frag-major basis (bi2f) + mel weights (wb) + basisEO (beo) ----------
__global__ void k_prep(const float* __restrict__ basis, const float* __restrict__ w,
                       unsigned short* __restrict__ bi2f, unsigned short* __restrict__ wb,
                       float* __restrict__ beo){
  int bx = blockIdx.x, tid = threadIdx.x;
  if (bx < 256){
    int CI = bx * 256 + tid;     // 65536 chunks
    int l  = CI & 63;
    int f  = (CI >> 6) & 7;
    int s  = (CI >> 9) & 15;
    int p  = (CI >> 13) & 1;
    int g  = CI >> 14;
    int R  = g * 128 + (f >> 2) * 64 + (f & 3) * 16 + (l & 15);
    int srcr = (R >> 1) + 513 * (R & 1);
    const float* sp = basis + srcr * 1024 + 2 * (s * 32 + (l >> 4) * 8) + p;
    bf16x8 o;
    #pragma unroll
    for (int e = 0; e < 8; ++e) o[e] = (short)f2bf(sp[2*e]);
    *(bf16x8*)(bi2f + (long)CI * 8) = o;
  } else {
    int gid = (bx - 256) * 256 + tid;    // 184 blocks worth: 46080 + 1024
    if (gid < NMELS * CPAD){
      int m = gid / CPAD, p = gid % CPAD;
      float v = 0.f;
      if (p <= 256) v = w[m * CUTOFF + p];
      else if (p >= 264 && p <= 519) v = w[m * CUTOFF + (p - 7)];
      wb[gid] = f2bf(v);
    } else if (gid < NMELS * CPAD + 1024){
      int g2 = gid - NMELS * CPAD;       // 0..1023
      int par = g2 >> 9, m = g2 & 511;
      beo[g2] = par ? basis[769 * 1024 + 2*m + 1] : basis[256 * 1024 + 2*m];
    }
  }
}

// ---------- k_extra: bin-256 value only (runs AFTER k_stft, overwrites its zero) ----------
__global__ void k_extra(const unsigned short* __restrict__ planes,
                        const float* __restrict__ beo,
                        unsigned short* __restrict__ magT){
  int tid = threadIdx.x, l = tid & 63, w = tid >> 6;
  long fr = (long)blockIdx.x * 4 + w;          // 0..32767
  int b = (int)(fr >> 10), t = (int)(fr & 1023);
  const unsigned short* pE = planes + (long)b * 2 * (PCH * 8);
  const unsigned short* pO = pE + PCH * 8;
  int idx = t * 128 + l * 8;                   // plane element index (origin-shifted)
  bf16x8 ev = *(const bf16x8*)(pE + idx);
  bf16x8 ov = *(const bf16x8*)(pO + idx);
  f32x4 be0 = *(const f32x4*)(beo + l*8);
  f32x4 be1 = *(const f32x4*)(beo + l*8 + 4);
  f32x4 bo0 = *(const f32x4*)(beo + 512 + l*8);
  f32x4 bo1 = *(const f32x4*)(beo + 512 + l*8 + 4);
  float re = bf2f(ev[0])*be0[0] + bf2f(ev[1])*be0[1] + bf2f(ev[2])*be0[2] + bf2f(ev[3])*be0[3]
           + bf2f(ev[4])*be1[0] + bf2f(ev[5])*be1[1] + bf2f(ev[6])*be1[2] + bf2f(ev[7])*be1[3];
  float im = bf2f(ov[0])*bo0[0] + bf2f(ov[1])*bo0[1] + bf2f(ov[2])*bo0[2] + bf2f(ov[3])*bo0[3]
           + bf2f(ov[4])*bo1[0] + bf2f(ov[5])*bo1[1] + bf2f(ov[6])*bo1[2] + bf2f(ov[7])*bo1[3];
  #pragma unroll
  for (int m = 1; m < 64; m <<= 1){
    re += __shfl_xor(re, m, 64);
    im += __shfl_xor(im, m, 64);
  }
  if (l == 0) magT[fr * CPAD + 256] = f2bf(sqrtf(re*re + im*im));
}

// ---------- k_stft: 128 M-rows x 64 frames, wave = 32M x 64F both parities ----------
// 4 waves/block, 4 blocks/CU; epilogue readout also zero-fills hole (g=3) / tail (g=0)
__launch_bounds__(256, 4)
__global__ void k_stft(const unsigned short* __restrict__ bi2f,
                       const unsigned short* __restrict__ planes,
                       unsigned short* __restrict__ magT){
  __shared__ __align__(16) char LDS[2 * EB64];   // 34304 B; epilogue tile 64x384B = 24576 B
  const int tid = threadIdx.x;
  const int l   = tid & 63, w = tid >> 6;        // w = wave id = 32-row slice
  const int x   = l & 15, h = l >> 4;

  int bx = blockIdx.x;
  int sw = ((bx & 7) << 8) | (bx >> 3);   // XCD swizzle (2048 % 8 == 0, bijective)
  const int g    = sw & 3;                // M group: interleaved rows [g*128, +128)
  const int nt64 = sw >> 2;               // 0..511 : frames [nt64*64, +64)

  // ---- stage 64-frame segment: linear dest, sigma-preswizzled source (rule #21) ----
  {
    const char* pb = (const char*)planes + (long)(nt64 >> 4) * 2 * PBYTES;
    const int kto = (nt64 & 15) * 1024;   // chunk offset, mult of 256 -> sigma invariant
    #pragma unroll
    for (int it = 0; it < 5; ++it){
      int o = it * 256 + tid;
      if (o < 1072){
        long so = (long)((o ^ ((o >> 4) & 15)) + kto) * 16;
        gload_lds16(pb + so,          LDS + o * 16);
        gload_lds16(pb + PBYTES + so, LDS + EB64 + o * 16);
      }
    }
  }
  asm volatile("s_waitcnt vmcnt(0)" ::: "memory");
  __syncthreads();

  // ---- A frag-major base: wave w owns frags f = 2w, 2w+1 of group g ----
  const char* Ab = (const char*)bi2f + (long)(g * 256 + 2 * w) * 1024 + l * 16;

  int C0[4];
  #pragma unroll
  for (int j = 0; j < 4; ++j) C0[j] = (j * 16 + x) * 16 + h;

  f32x4 accE[2][4] = {}, accO[2][4] = {};

  #pragma unroll
  for (int s = 0; s < 16; ++s){
    bf16x8 aE0 = *(const bf16x8*)(Ab + s * 8192);
    bf16x8 aE1 = *(const bf16x8*)(Ab + s * 8192 + 1024);
    bf16x8 aO0 = *(const bf16x8*)(Ab + 131072 + s * 8192);
    bf16x8 aO1 = *(const bf16x8*)(Ab + 131072 + s * 8192 + 1024);
    bf16x8 bqE[4], bqO[4];
    #pragma unroll
    for (int j = 0; j < 4; ++j){
      int C = C0[j] + s * 4; int ad = (C ^ ((C >> 4) & 15)) << 4;
      bqE[j] = *(const bf16x8*)(LDS + ad);
      bqO[j] = *(const bf16x8*)(LDS + EB64 + ad);
    }
    __builtin_amdgcn_s_setprio(1);
    #pragma unroll
    for (int j = 0; j < 4; ++j){
      accE[0][j] = __builtin_amdgcn_mfma_f32_16x16x32_bf16(aE0, bqE[j], accE[0][j], 0, 0, 0);
      accE[1][j] = __builtin_amdgcn_mfma_f32_16x16x32_bf16(aE1, bqE[j], accE[1][j], 0, 0, 0);
    }
    #pragma unroll
    for (int j = 0; j < 4; ++j){
      accO[0][j] = __builtin_amdgcn_mfma_f32_16x16x32_bf16(aO0, bqO[j], accO[0][j], 0, 0, 0);
      accO[1][j] = __builtin_amdgcn_mfma_f32_16x16x32_bf16(aO1, bqO[j], accO[1][j], 0, 0, 0);
    }
    __builtin_amdgcn_s_setprio(0);
  }

  // ---- transpose fill: u32 tile [64 tl][96-slot pitch(384B)], slot ^= (tl&7)<<2 (slots<64) ----
  __syncthreads();   // all K-loop LDS reads done; safe to overwrite audio planes
  if (g == 0){       // tail extension slots 64..91 (cols 520..575) = zeros
    #pragma unroll
    for (int z = 0; z < 7; ++z){
      int id = z * 256 + tid;              // 1792 = 64 tl x 28 slots
      int tl = id / 28, sl = 64 + id % 28;
      *(unsigned*)(LDS + tl * 384 + sl * 4) = 0;
    }
  } else if (g == 3){ // hole extension slots 64..67 (cols 256..263) = zeros
    int tl = tid >> 2, sl = 64 + (tid & 3);
    *(unsigned*)(LDS + tl * 384 + sl * 4) = 0;
  }
  #pragma unroll
  for (int i = 0; i < 2; ++i){
    int cp1 = w * 8 + i * 4 + h;            // 0..31 -> c0 = g*64 + 2*cp1
    int sm  = 63 - cp1;                     // 32..63 -> p = 518-c0, 519-c0
    #pragma unroll
    for (int j = 0; j < 4; ++j){
      int tl = j * 16 + x;
      f32x4 E = accE[i][j], O = accO[i][j];
      float m1 = sqrtf((E[0]+O[0])*(E[0]+O[0]) + (E[1]+O[1])*(E[1]+O[1]));  // X[c0]
      float m2 = sqrtf((E[2]+O[2])*(E[2]+O[2]) + (E[3]+O[3])*(E[3]+O[3]));  // X[c0+1]
      float m3 = sqrtf((E[0]-O[0])*(E[0]-O[0]) + (E[1]-O[1])*(E[1]-O[1]));  // X[512-c0]
      float m4 = sqrtf((E[2]-O[2])*(E[2]-O[2]) + (E[3]-O[3])*(E[3]-O[3]));  // X[511-c0]
      unsigned p1 = (unsigned)f2bf(m1) | ((unsigned)f2bf(m2) << 16);
      unsigned p2 = (unsigned)f2bf(m4) | ((unsigned)f2bf(m3) << 16);
      int xs = (tl & 7) << 2;
      *(unsigned*)(LDS + tl * 384 + ((cp1 ^ xs) << 2)) = p1;
      *(unsigned*)(LDS + tl * 384 + ((sm  ^ xs) << 2)) = p2;
    }
  }
  __syncthreads();

  // ---- coalesced readout: 8 passes, 16B/thread; per-g group count ----
  {
    const long rowbase = (long)(nt64 * 64) * CPAD;
    int grp = tid & 31, rr = tid >> 5;      // 32 slot-groups x 8 rows
    int ngrp = (g == 0) ? 23 : (g == 3) ? 17 : 16;
    int cb0;
    if (grp < 8)       cb0 = g * 64 + grp * 8;
    else if (grp < 16) cb0 = 456 - 64 * g + (grp - 8) * 8;
    else               cb0 = ((g == 0) ? 520 : 256) + (grp - 16) * 8;
    #pragma unroll
    for (int pass = 0; pass < 8; ++pass){
      int tl = pass * 8 + rr;
      if (grp < ngrp){
        int f4 = (grp < 16) ? ((grp * 4) ^ ((tl & 7) << 2)) : (grp * 4);
        i32x4 vv = *(const i32x4*)(LDS + tl * 384 + f4 * 4);
        *(i32x4*)((char*)magT + (rowbase + (long)tl * CPAD + cb0) * 2) = vv;
      }
    }
  }
}

// ---------- k_mel: 512 blocks (64-wide t tiles), pair-line-swizzled LDS ----------
__launch_bounds__(256)
__global__ void k_mel(const unsigned short* __restrict__ wb,
                      const unsigned short* __restrict__ magT,
                      float* __restrict__ out){
  __shared__ unsigned short Ws[80 * 32];    // 5120 B, pair-line swizzle
  __shared__ unsigned short Ms[64 * 32];    // 4096 B, pair-line swizzle
  int tid = threadIdx.x, l = tid & 63, w = tid >> 6;
  int x = l & 15, h = l >> 4;
  int bx = blockIdx.x;
  int bt = bx & 15, b = bx >> 4;
  int t0 = bt * 64;
  f32x4 acc[5] = {};
  const char* Mb = (const char*)(magT + ((long)b * 1024 + t0) * CPAD);
  const char* Wb = (const char*)wb;

  for (int kt = 0; kt < 18; ++kt){
    int k0b = kt * 64;
    // stage Ws (320 chunks): chunk d -> pairline pl=d>>3, swz slot sl=(d&7)^(pl&7)
    {
      int pl = tid >> 3, sl = (tid & 7) ^ (pl & 7);
      gload_lds16(Wb + (pl * 2 + (sl >> 2)) * 1152 + k0b + (sl & 3) * 16, (char*)Ws + tid * 16);
      if (w == 0){
        int d2 = 256 + l;
        int pl2 = d2 >> 3, sl2 = (d2 & 7) ^ (pl2 & 7);
        gload_lds16(Wb + (pl2 * 2 + (sl2 >> 2)) * 1152 + k0b + (sl2 & 3) * 16, (char*)Ws + d2 * 16);
      }
    }
    // stage Ms (256 chunks)
    {
      int pl = tid >> 3, sl = (tid & 7) ^ (pl & 7);
      gload_lds16(Mb + (long)(pl * 2 + (sl >> 2)) * 1152 + k0b + (sl & 3) * 16, (char*)Ms + tid * 16);
    }
    __syncthreads();
    bf16x8 af[5], bfr;
    #pragma unroll
    for (int i = 0; i < 5; ++i){
      int row = i * 16 + x;
      int pl = row >> 1, sl = (((row & 1) << 2) + h) ^ (pl & 7);
      af[i] = *(const bf16x8*)((const char*)Ws + pl * 128 + sl * 16);
    }
    {
      int row = w * 16 + x;
      int pl = row >> 1, sl = (((row & 1) << 2) + h) ^ (pl & 7);
      bfr = *(const bf16x8*)((const char*)Ms + pl * 128 + sl * 16);
    }
    #pragma unroll
    for (int i = 0; i < 5; ++i)
      acc[i] = __builtin_amdgcn_mfma_f32_16x16x32_bf16(af[i], bfr, acc[i], 0, 0, 0);
    __syncthreads();
  }
  int t = t0 + w * 16 + x;
  #pragma unroll
  for (int i = 0; i < 5; ++i){
    int m = i * 16 + (h << 2);
    #pragma unroll
    for (int r = 0; r < 4; ++r)
      out[((long)b * NMELS + (m + r)) * 1024 + t] = logf(fmaxf(acc[i][r], 1e-5f));
  }
}

__global__ void k_sentinel(float* out, int n){
  int i = blockIdx.x * 256 + threadIdx.x;
  if (i < n) out[i] = 12345.0f;
}

extern "C" void kernel_launch(void* const* d_in, const int* in_sizes, int n_in,
                              void* d_out, int out_size, void* d_ws, size_t ws_size,
                              hipStream_t stream){
  const float* audio = (const float*)d_in[0];
  const float* basis = (const float*)d_in[1];
  const float* melw  = (const float*)d_in[2];
  float* out = (float*)d_out;

  size_t off_bi  = 0;                                            // bi2f: 1 MB
  size_t off_wb  = (size_t)1024 * 1024;
  size_t off_beo = off_wb + (size_t)NMELS * CPAD * 2;            // 4 KB f32 basisEO
  size_t off_mag = off_beo + 1024 * 4;
  size_t off_pl  = off_mag + (size_t)32 * 1024 * CPAD * 2;
  size_t total   = off_pl + (size_t)32 * 2 * PBYTES;             // ~55.7 MB

  if (ws_size < total){
    k_sentinel<<<(out_size + 255) / 256, 256, 0, stream>>>(out, out_size);
    return;
  }
  char* ws = (char*)d_ws;
  unsigned short* bi2f   = (unsigned short*)(ws + off_bi);
  unsigned short* wb     = (unsigned short*)(ws + off_wb);
  float*          beo    = (float*)(ws + off_beo);
  unsigned short* magT   = (unsigned short*)(ws + off_mag);
  unsigned short* planes = (unsigned short*)(ws + off_pl);

  k_prep  <<<  440, 256, 0, stream>>>(basis, melw, bi2f, wb, beo);
  k_audio <<< 2080, 256, 0, stream>>>(audio, planes);
  k_stft  <<< 2048, 256, 0, stream>>>(bi2f, planes, magT);
  k_extra <<< 8192, 256, 0, stream>>>(planes, beo, magT);
  k_mel   <<<  512, 256, 0, stream>>>(wb, magT, out);
}

// Round 17
// 77.720 us; speedup vs baseline: 1.0063x; 1.0063x over previous
//
#include <hip/hip_runtime.h>
#include <hip/hip_bf16.h>

typedef short bf16x8 __attribute__((ext_vector_type(8)));
typedef float f32x4  __attribute__((ext_vector_type(4)));
typedef int   i32x4  __attribute__((ext_vector_type(4)));

#define T_AUDIO 262144
#define PADL 384
#define CUTOFF 513
#define CPAD 576       // layout: p=c for c<=256, hole 257..263, p=c+7 for c>=257, tail 520..575 zero
#define NMELS 80
#define PCH 16448      // chunks per global plane (per b, per parity)
#define PBYTES (PCH*16)
#define EB64 17152     // bytes per parity plane in LDS (1072 chunks, 64-frame segment)

__device__ __forceinline__ unsigned short f2bf(float f){
  union { float f; unsigned u; } v; v.f = f;
  return (unsigned short)((v.u + 0x7FFFu + ((v.u >> 16) & 1u)) >> 16);
}
__device__ __forceinline__ float bf2f(unsigned short u){
  union { unsigned u; float f; } v; v.u = (unsigned)u << 16; return v.f;
}

__device__ __forceinline__ void gload_lds16(const void* g, void* l){
  __builtin_amdgcn_global_load_lds(
      (const __attribute__((address_space(1))) unsigned int*)g,
      (__attribute__((address_space(3))) unsigned int*)l, 16, 0, 0);
}

// ---------- k_audio: reflect-padded bf16 E/O planes, natural layout ----------
__global__ void k_audio(const float* __restrict__ audio, unsigned short* __restrict__ planes){
  int bx = blockIdx.x;              // 2080 blocks = 32 b x 65
  int b  = bx / 65;
  int ci = (bx % 65) * 256 + threadIdx.x;
  if (ci >= PCH) return;
  const float* ap = audio + (long)b * T_AUDIO;
  int s0 = 16 * ci - 384;
  float v[16];
  if (s0 >= 0 && s0 + 15 < T_AUDIO){
    #pragma unroll
    for (int q = 0; q < 4; ++q){
      f32x4 a = *(const f32x4*)(ap + s0 + q * 4);
      v[q*4]=a[0]; v[q*4+1]=a[1]; v[q*4+2]=a[2]; v[q*4+3]=a[3];
    }
  } else {
    #pragma unroll
    for (int e = 0; e < 16; ++e){
      int s = s0 + e;
      if (s < 0) s = -s;
      if (s >= T_AUDIO) s = 2*(T_AUDIO-1) - s;
      v[e] = ap[s];
    }
  }
  bf16x8 ev, ov;
  #pragma unroll
  for (int e = 0; e < 8; ++e){
    ev[e] = (short)f2bf(v[2*e]);
    ov[e] = (short)f2bf(v[2*e+1]);
  }
  unsigned short* pE = planes + (long)b * 2 * (PCH * 8);
  *(bf16x8*)(pE + (long)ci * 8)            = ev;
  *(bf16x8*)(pE + PCH * 8 + (long)ci * 8)  = ov;
}

// ---------- k_prep: frag-major basis (bi2f) + mel weights (wb) + basisEO (beo) ----------
__global__ void k_prep(const float* __restrict__ basis, const float* __restrict__ w,
                       unsigned short* __restrict__ bi2f, unsigned short* __restrict__ wb,
                       float* __restrict__ beo){
  int bx = blockIdx.x, tid = threadIdx.x;
  if (bx < 256){
    int CI = bx * 256 + tid;     // 65536 chunks
    int l  = CI & 63;
    int f  = (CI >> 6) & 7;
    int s  = (CI >> 9) & 15;
    int p  = (CI >> 13) & 1;
    int g  = CI >> 14;
    int R  = g * 128 + (f >> 2) * 64 + (f & 3) * 16 + (l & 15);
    int srcr = (R >> 1) + 513 * (R & 1);
    const float* sp = basis + srcr * 1024 + 2 * (s * 32 + (l >> 4) * 8) + p;
    bf16x8 o;
    #pragma unroll
    for (int e = 0; e < 8; ++e) o[e] = (short)f2bf(sp[2*e]);
    *(bf16x8*)(bi2f + (long)CI * 8) = o;
  } else {
    int gid = (bx - 256) * 256 + tid;    // 184 blocks worth: 46080 + 1024
    if (gid < NMELS * CPAD){
      int m = gid / CPAD, p = gid % CPAD;
      float v = 0.f;
      if (p <= 256) v = w[m * CUTOFF + p];
      else if (p >= 264 && p <= 519) v = w[m * CUTOFF + (p - 7)];
      wb[gid] = f2bf(v);
    } else if (gid < NMELS * CPAD + 1024){
      int g2 = gid - NMELS * CPAD;       // 0..1023
      int par = g2 >> 9, m = g2 & 511;
      beo[g2] = par ? basis[769 * 1024 + 2*m + 1] : basis[256 * 1024 + 2*m];
    }
  }
}

// ---------- k_extra: bin-256 value + zero pad cols (hole 257..263, tail 520..575) ----------
__global__ void k_extra(const unsigned short* __restrict__ planes,
                        const float* __restrict__ beo,
                        unsigned short* __restrict__ magT){
  int tid = threadIdx.x, l = tid & 63, w = tid >> 6;
  long fr = (long)blockIdx.x * 4 + w;          // 0..32767
  int b = (int)(fr >> 10), t = (int)(fr & 1023);
  const unsigned short* pE = planes + (long)b * 2 * (PCH * 8);
  const unsigned short* pO = pE + PCH * 8;
  int idx = t * 128 + l * 8;                   // plane element index (origin-shifted)
  bf16x8 ev = *(const bf16x8*)(pE + idx);
  bf16x8 ov = *(const bf16x8*)(pO + idx);
  f32x4 be0 = *(const f32x4*)(beo + l*8);
  f32x4 be1 = *(const f32x4*)(beo + l*8 + 4);
  f32x4 bo0 = *(const f32x4*)(beo + 512 + l*8);
  f32x4 bo1 = *(const f32x4*)(beo + 512 + l*8 + 4);
  float re = bf2f(ev[0])*be0[0] + bf2f(ev[1])*be0[1] + bf2f(ev[2])*be0[2] + bf2f(ev[3])*be0[3]
           + bf2f(ev[4])*be1[0] + bf2f(ev[5])*be1[1] + bf2f(ev[6])*be1[2] + bf2f(ev[7])*be1[3];
  float im = bf2f(ov[0])*bo0[0] + bf2f(ov[1])*bo0[1] + bf2f(ov[2])*bo0[2] + bf2f(ov[3])*bo0[3]
           + bf2f(ov[4])*bo1[0] + bf2f(ov[5])*bo1[1] + bf2f(ov[6])*bo1[2] + bf2f(ov[7])*bo1[3];
  #pragma unroll
  for (int m = 1; m < 64; m <<= 1){
    re += __shfl_xor(re, m, 64);
    im += __shfl_xor(im, m, 64);
  }
  long tg = fr * CPAD;
  if (l == 0) magT[tg + 256] = f2bf(sqrtf(re*re + im*im));
  if (l < 63){
    int p = (l < 7) ? (257 + l) : (513 + l);   // hole 257..263, tail 520..575
    magT[tg + p] = 0;
  }
}

// ---------- k_stft: 128 M-rows x 64 frames, wave = 32M x 64F both parities ----------
// 4 waves/block, 64 arch VGPR + 64 AGPR -> 4 blocks/CU = 4 waves/SIMD
__launch_bounds__(256, 4)
__global__ void k_stft(const unsigned short* __restrict__ bi2f,
                       const unsigned short* __restrict__ planes,
                       unsigned short* __restrict__ magT){
  __shared__ __align__(16) char LDS[2 * EB64];   // 34304 B; epilogue tile reuses 16 KB
  const int tid = threadIdx.x;
  const int l   = tid & 63, w = tid >> 6;        // w = wave id = 32-row slice
  const int x   = l & 15, h = l >> 4;

  int bx = blockIdx.x;
  int sw = ((bx & 7) << 8) | (bx >> 3);   // XCD swizzle (2048 % 8 == 0, bijective)
  const int g    = sw & 3;                // M group: interleaved rows [g*128, +128)
  const int nt64 = sw >> 2;               // 0..511 : frames [nt64*64, +64)

  // ---- stage 64-frame segment: linear dest, sigma-preswizzled source (rule #21) ----
  {
    const char* pb = (const char*)planes + (long)(nt64 >> 4) * 2 * PBYTES;
    const int kto = (nt64 & 15) * 1024;   // chunk offset, mult of 256 -> sigma invariant
    #pragma unroll
    for (int it = 0; it < 5; ++it){
      int o = it * 256 + tid;
      if (o < 1072){
        long so = (long)((o ^ ((o >> 4) & 15)) + kto) * 16;
        gload_lds16(pb + so,          LDS + o * 16);
        gload_lds16(pb + PBYTES + so, LDS + EB64 + o * 16);
      }
    }
  }
  asm volatile("s_waitcnt vmcnt(0)" ::: "memory");
  __syncthreads();

  // ---- A frag-major base: wave w owns frags f = 2w, 2w+1 of group g ----
  const char* Ab = (const char*)bi2f + (long)(g * 256 + 2 * w) * 1024 + l * 16;

  int C0[4];
  #pragma unroll
  for (int j = 0; j < 4; ++j) C0[j] = (j * 16 + x) * 16 + h;

  f32x4 accE[2][4] = {}, accO[2][4] = {};

  #pragma unroll
  for (int s = 0; s < 16; ++s){
    bf16x8 aE0 = *(const bf16x8*)(Ab + s * 8192);
    bf16x8 aE1 = *(const bf16x8*)(Ab + s * 8192 + 1024);
    bf16x8 aO0 = *(const bf16x8*)(Ab + 131072 + s * 8192);
    bf16x8 aO1 = *(const bf16x8*)(Ab + 131072 + s * 8192 + 1024);
    bf16x8 bqE[4], bqO[4];
    #pragma unroll
    for (int j = 0; j < 4; ++j){
      int C = C0[j] + s * 4; int ad = (C ^ ((C >> 4) & 15)) << 4;
      bqE[j] = *(const bf16x8*)(LDS + ad);
      bqO[j] = *(const bf16x8*)(LDS + EB64 + ad);
    }
    __builtin_amdgcn_s_setprio(1);
    #pragma unroll
    for (int j = 0; j < 4; ++j){
      accE[0][j] = __builtin_amdgcn_mfma_f32_16x16x32_bf16(aE0, bqE[j], accE[0][j], 0, 0, 0);
      accE[1][j] = __builtin_amdgcn_mfma_f32_16x16x32_bf16(aE1, bqE[j], accE[1][j], 0, 0, 0);
    }
    #pragma unroll
    for (int j = 0; j < 4; ++j){
      accO[0][j] = __builtin_amdgcn_mfma_f32_16x16x32_bf16(aO0, bqO[j], accO[0][j], 0, 0, 0);
      accO[1][j] = __builtin_amdgcn_mfma_f32_16x16x32_bf16(aO1, bqO[j], accO[1][j], 0, 0, 0);
    }
    __builtin_amdgcn_s_setprio(0);
  }

  // ---- transpose fill: u32 tile [64 tl][64 slots], slot ^= (tl&7)<<2 ----
  // direct pair-slot cp1 = w*8+i*4+h -> c0 = g*64 + 2*cp1 (m1@c0, m2@c0+1)
  // mirror slot 63-cp1 -> (m4@p=518-c0, m3@p=519-c0) in shifted (+7) layout
  __syncthreads();   // all K-loop LDS reads done; safe to overwrite audio planes
  #pragma unroll
  for (int i = 0; i < 2; ++i){
    int cp1 = w * 8 + i * 4 + h;            // 0..31
    int sm  = 63 - cp1;                     // 32..63
    #pragma unroll
    for (int j = 0; j < 4; ++j){
      int tl = j * 16 + x;
      f32x4 E = accE[i][j], O = accO[i][j];
      float m1 = sqrtf((E[0]+O[0])*(E[0]+O[0]) + (E[1]+O[1])*(E[1]+O[1]));  // X[c0]
      float m2 = sqrtf((E[2]+O[2])*(E[2]+O[2]) + (E[3]+O[3])*(E[3]+O[3]));  // X[c0+1]
      float m3 = sqrtf((E[0]-O[0])*(E[0]-O[0]) + (E[1]-O[1])*(E[1]-O[1]));  // X[512-c0]
      float m4 = sqrtf((E[2]-O[2])*(E[2]-O[2]) + (E[3]-O[3])*(E[3]-O[3]));  // X[511-c0]
      unsigned p1 = (unsigned)f2bf(m1) | ((unsigned)f2bf(m2) << 16);
      unsigned p2 = (unsigned)f2bf(m4) | ((unsigned)f2bf(m3) << 16);
      int xs = (tl & 7) << 2;
      *(unsigned*)(LDS + tl * 256 + ((cp1 ^ xs) << 2)) = p1;
      *(unsigned*)(LDS + tl * 256 + ((sm  ^ xs) << 2)) = p2;
    }
  }
  __syncthreads();

  // ---- coalesced readout: 4 passes, 16B/thread; direct [64g,+64), mirror [456-64g,+64) ----
  {
    const long rowbase = (long)(nt64 * 64) * CPAD;
    int grp = tid & 15, rr = tid >> 4;      // 16 slot-groups x 16 rows
    int cb0 = (grp < 8) ? (g * 64 + grp * 8) : (456 - 64 * g + (grp - 8) * 8);
    #pragma unroll
    for (int pass = 0; pass < 4; ++pass){
      int tl = pass * 16 + rr;
      int f4 = (grp * 4) ^ ((tl & 7) << 2);
      i32x4 vv = *(const i32x4*)(LDS + tl * 256 + f4 * 4);
      *(i32x4*)((char*)magT + (rowbase + (long)tl * CPAD + cb0) * 2) = vv;
    }
  }
}

// ---------- k_mel: 512 blocks (64-wide t tiles), pair-line-swizzled LDS ----------
__launch_bounds__(256)
__global__ void k_mel(const unsigned short* __restrict__ wb,
                      const unsigned short* __restrict__ magT,
                      float* __restrict__ out){
  __shared__ unsigned short Ws[80 * 32];    // 5120 B, pair-line swizzle
  __shared__ unsigned short Ms[64 * 32];    // 4096 B, pair-line swizzle
  int tid = threadIdx.x, l = tid & 63, w = tid >> 6;
  int x = l & 15, h = l >> 4;
  int bx = blockIdx.x;
  int bt = bx & 15, b = bx >> 4;
  int t0 = bt * 64;
  f32x4 acc[5] = {};
  const char* Mb = (const char*)(magT + ((long)b * 1024 + t0) * CPAD);
  const char* Wb = (const char*)wb;

  for (int kt = 0; kt < 18; ++kt){
    int k0b = kt * 64;
    // stage Ws (320 chunks): chunk d -> pairline pl=d>>3, swz slot sl=(d&7)^(pl&7)
    {
      int pl = tid >> 3, sl = (tid & 7) ^ (pl & 7);
      gload_lds16(Wb + (pl * 2 + (sl >> 2)) * 1152 + k0b + (sl & 3) * 16, (char*)Ws + tid * 16);
      if (w == 0){
        int d2 = 256 + l;
        int pl2 = d2 >> 3, sl2 = (d2 & 7) ^ (pl2 & 7);
        gload_lds16(Wb + (pl2 * 2 + (sl2 >> 2)) * 1152 + k0b + (sl2 & 3) * 16, (char*)Ws + d2 * 16);
      }
    }
    // stage Ms (256 chunks)
    {
      int pl = tid >> 3, sl = (tid & 7) ^ (pl & 7);
      gload_lds16(Mb + (long)(pl * 2 + (sl >> 2)) * 1152 + k0b + (sl & 3) * 16, (char*)Ms + tid * 16);
    }
    __syncthreads();
    bf16x8 af[5], bfr;
    #pragma unroll
    for (int i = 0; i < 5; ++i){
      int row = i * 16 + x;
      int pl = row >> 1, sl = (((row & 1) << 2) + h) ^ (pl & 7);
      af[i] = *(const bf16x8*)((const char*)Ws + pl * 128 + sl * 16);
    }
    {
      int row = w * 16 + x;
      int pl = row >> 1, sl = (((row & 1) << 2) + h) ^ (pl & 7);
      bfr = *(const bf16x8*)((const char*)Ms + pl * 128 + sl * 16);
    }
    #pragma unroll
    for (int i = 0; i < 5; ++i)
      acc[i] = __builtin_amdgcn_mfma_f32_16x16x32_bf16(af[i], bfr, acc[i], 0, 0, 0);
    __syncthreads();
  }
  int t = t0 + w * 16 + x;
  #pragma unroll
  for (int i = 0; i < 5; ++i){
    int m = i * 16 + (h << 2);
    #pragma unroll
    for (int r = 0; r < 4; ++r)
      out[((long)b * NMELS + (m + r)) * 1024 + t] = logf(fmaxf(acc[i][r], 1e-5f));
  }
}

__global__ void k_sentinel(float* out, int n){
  int i = blockIdx.x * 256 + threadIdx.x;
  if (i < n) out[i] = 12345.0f;
}

extern "C" void kernel_launch(void* const* d_in, const int* in_sizes, int n_in,
                              void* d_out, int out_size, void* d_ws, size_t ws_size,
                              hipStream_t stream){
  const float* audio = (const float*)d_in[0];
  const float* basis = (const float*)d_in[1];
  const float* melw  = (const float*)d_in[2];
  float* out = (float*)d_out;

  size_t off_bi  = 0;                                            // bi2f: 1 MB
  size_t off_wb  = (size_t)1024 * 1024;
  size_t off_beo = off_wb + (size_t)NMELS * CPAD * 2;            // 4 KB f32 basisEO
  size_t off_mag = off_beo + 1024 * 4;
  size_t off_pl  = off_mag + (size_t)32 * 1024 * CPAD * 2;
  size_t total   = off_pl + (size_t)32 * 2 * PBYTES;             // ~55.7 MB

  if (ws_size < total){
    k_sentinel<<<(out_size + 255) / 256, 256, 0, stream>>>(out, out_size);
    return;
  }
  char* ws = (char*)d_ws;
  unsigned short* bi2f   = (unsigned short*)(ws + off_bi);
  unsigned short* wb     = (unsigned short*)(ws + off_wb);
  float*          beo    = (float*)(ws + off_beo);
  unsigned short* magT   = (unsigned short*)(ws + off_mag);
  unsigned short* planes = (unsigned short*)(ws + off_pl);

  k_prep  <<<  440, 256, 0, stream>>>(basis, melw, bi2f, wb, beo);
  k_audio <<< 2080, 256, 0, stream>>>(audio, planes);
  k_stft  <<< 2048, 256, 0, stream>>>(bi2f, planes, magT);
  k_extra <<< 8192, 256, 0, stream>>>(planes, beo, magT);
  k_mel   <<<  512, 256, 0, stream>>>(wb, magT, out);
}

// Round 18
// 69.899 us; speedup vs baseline: 1.1188x; 1.1119x over previous
//
#include <hip/hip_runtime.h>
#include <hip/hip_bf16.h>

typedef short bf16x8 __attribute__((ext_vector_type(8)));
typedef float f32x4  __attribute__((ext_vector_type(4)));
typedef int   i32x4  __attribute__((ext_vector_type(4)));

#define T_AUDIO 262144
#define PADL 384
#define CUTOFF 513
#define CPAD 576       // layout: p=c for c<=256, hole 257..263, p=c+7 for c>=257, tail 520..575 zero
#define NMELS 80
#define PCH 16448      // chunks per global plane (per b, per parity)
#define PBYTES (PCH*16)
#define EB64 17152     // bytes per parity plane in LDS (1072 chunks, 64-frame segment)

__device__ __forceinline__ unsigned short f2bf(float f){
  union { float f; unsigned u; } v; v.f = f;
  return (unsigned short)((v.u + 0x7FFFu + ((v.u >> 16) & 1u)) >> 16);
}
__device__ __forceinline__ float bf2f(unsigned short u){
  union { unsigned u; float f; } v; v.u = (unsigned)u << 16; return v.f;
}
__device__ __forceinline__ float fsqrt_a(float x){   // 1-instr approx sqrt (~1ulp): bf16 output
  float r; asm("v_sqrt_f32 %0, %1" : "=v"(r) : "v"(x)); return r;
}
__device__ __forceinline__ float flog_a(float x){    // log(x) = log2(x)*ln2, ~1e-6 abs err
  float r; asm("v_log_f32 %0, %1" : "=v"(r) : "v"(x)); return r * 0.6931471805599453f;
}

__device__ __forceinline__ void gload_lds16(const void* g, void* l){
  __builtin_amdgcn_global_load_lds(
      (const __attribute__((address_space(1))) unsigned int*)g,
      (__attribute__((address_space(3))) unsigned int*)l, 16, 0, 0);
}

// ---------- k_audio_prep: audio planes (blocks 0..2079) + basis/mel prep (2080..2519) ----------
__global__ void k_audio_prep(const float* __restrict__ audio, const float* __restrict__ basis,
                             const float* __restrict__ w,
                             unsigned short* __restrict__ planes,
                             unsigned short* __restrict__ bi2f,
                             unsigned short* __restrict__ wb,
                             float* __restrict__ beo){
  int bx = blockIdx.x, tid = threadIdx.x;
  if (bx < 2080){
    int b  = bx / 65;
    int ci = (bx % 65) * 256 + tid;
    if (ci >= PCH) return;
    const float* ap = audio + (long)b * T_AUDIO;
    int s0 = 16 * ci - 384;
    float v[16];
    if (s0 >= 0 && s0 + 15 < T_AUDIO){
      #pragma unroll
      for (int q = 0; q < 4; ++q){
        f32x4 a = *(const f32x4*)(ap + s0 + q * 4);
        v[q*4]=a[0]; v[q*4+1]=a[1]; v[q*4+2]=a[2]; v[q*4+3]=a[3];
      }
    } else {
      #pragma unroll
      for (int e = 0; e < 16; ++e){
        int s = s0 + e;
        if (s < 0) s = -s;
        if (s >= T_AUDIO) s = 2*(T_AUDIO-1) - s;
        v[e] = ap[s];
      }
    }
    bf16x8 ev, ov;
    #pragma unroll
    for (int e = 0; e < 8; ++e){
      ev[e] = (short)f2bf(v[2*e]);
      ov[e] = (short)f2bf(v[2*e+1]);
    }
    unsigned short* pE = planes + (long)b * 2 * (PCH * 8);
    *(bf16x8*)(pE + (long)ci * 8)            = ev;
    *(bf16x8*)(pE + PCH * 8 + (long)ci * 8)  = ov;
  } else if (bx < 2336){
    int CI = (bx - 2080) * 256 + tid;     // 65536 chunks
    int l  = CI & 63;
    int f  = (CI >> 6) & 7;
    int s  = (CI >> 9) & 15;
    int p  = (CI >> 13) & 1;
    int g  = CI >> 14;
    int R  = g * 128 + (f >> 2) * 64 + (f & 3) * 16 + (l & 15);
    int srcr = (R >> 1) + 513 * (R & 1);
    const float* sp = basis + srcr * 1024 + 2 * (s * 32 + (l >> 4) * 8) + p;
    bf16x8 o;
    #pragma unroll
    for (int e = 0; e < 8; ++e) o[e] = (short)f2bf(sp[2*e]);
    *(bf16x8*)(bi2f + (long)CI * 8) = o;
  } else {
    int gid = (bx - 2336) * 256 + tid;    // 46080 + 1024
    if (gid < NMELS * CPAD){
      int m = gid / CPAD, p = gid % CPAD;
      float v = 0.f;
      if (p <= 256) v = w[m * CUTOFF + p];
      else if (p >= 264 && p <= 519) v = w[m * CUTOFF + (p - 7)];
      wb[gid] = f2bf(v);
    } else if (gid < NMELS * CPAD + 1024){
      int g2 = gid - NMELS * CPAD;
      int par = g2 >> 9, m = g2 & 511;
      beo[g2] = par ? basis[769 * 1024 + 2*m + 1] : basis[256 * 1024 + 2*m];
    }
  }
}

// ---------- k_stft: blocks [0,2048) = E/O GEMM ; blocks [2048,10240) = bin-256 + pad cols ----------
__launch_bounds__(256, 4)
__global__ void k_stft(const unsigned short* __restrict__ bi2f,
                       const unsigned short* __restrict__ planes,
                       const float* __restrict__ beo,
                       unsigned short* __restrict__ magT){
  __shared__ __align__(16) char LDS[2 * EB64];   // 34304 B; epilogue tile reuses 16 KB
  const int tid = threadIdx.x;
  const int l   = tid & 63, w = tid >> 6;
  const int x   = l & 15, h = l >> 4;

  int bx = blockIdx.x;
  if (bx >= 2048){
    // ---- extra path: bin-256 value + zero pad cols (hole 257..263, tail 520..575) ----
    long fr = (long)(bx - 2048) * 4 + w;         // 0..32767
    int b = (int)(fr >> 10), t = (int)(fr & 1023);
    const unsigned short* pE = planes + (long)b * 2 * (PCH * 8);
    const unsigned short* pO = pE + PCH * 8;
    int idx = t * 128 + l * 8;
    bf16x8 ev = *(const bf16x8*)(pE + idx);
    bf16x8 ov = *(const bf16x8*)(pO + idx);
    f32x4 be0 = *(const f32x4*)(beo + l*8);
    f32x4 be1 = *(const f32x4*)(beo + l*8 + 4);
    f32x4 bo0 = *(const f32x4*)(beo + 512 + l*8);
    f32x4 bo1 = *(const f32x4*)(beo + 512 + l*8 + 4);
    float re = bf2f(ev[0])*be0[0] + bf2f(ev[1])*be0[1] + bf2f(ev[2])*be0[2] + bf2f(ev[3])*be0[3]
             + bf2f(ev[4])*be1[0] + bf2f(ev[5])*be1[1] + bf2f(ev[6])*be1[2] + bf2f(ev[7])*be1[3];
    float im = bf2f(ov[0])*bo0[0] + bf2f(ov[1])*bo0[1] + bf2f(ov[2])*bo0[2] + bf2f(ov[3])*bo0[3]
             + bf2f(ov[4])*bo1[0] + bf2f(ov[5])*bo1[1] + bf2f(ov[6])*bo1[2] + bf2f(ov[7])*bo1[3];
    #pragma unroll
    for (int m = 1; m < 64; m <<= 1){
      re += __shfl_xor(re, m, 64);
      im += __shfl_xor(im, m, 64);
    }
    long tg = fr * CPAD;
    if (l == 0) magT[tg + 256] = f2bf(fsqrt_a(re*re + im*im));
    if (l < 63){
      int p = (l < 7) ? (257 + l) : (513 + l);
      magT[tg + p] = 0;
    }
    return;
  }

  int sw = ((bx & 7) << 8) | (bx >> 3);   // XCD swizzle (2048 % 8 == 0, bijective)
  const int g    = sw & 3;                // M group: interleaved rows [g*128, +128)
  const int nt64 = sw >> 2;               // 0..511 : frames [nt64*64, +64)

  // ---- stage 64-frame segment: linear dest, sigma-preswizzled source (rule #21) ----
  {
    const char* pb = (const char*)planes + (long)(nt64 >> 4) * 2 * PBYTES;
    const int kto = (nt64 & 15) * 1024;   // chunk offset, mult of 256 -> sigma invariant
    #pragma unroll
    for (int it = 0; it < 5; ++it){
      int o = it * 256 + tid;
      if (o < 1072){
        long so = (long)((o ^ ((o >> 4) & 15)) + kto) * 16;
        gload_lds16(pb + so,          LDS + o * 16);
        gload_lds16(pb + PBYTES + so, LDS + EB64 + o * 16);
      }
    }
  }
  asm volatile("s_waitcnt vmcnt(0)" ::: "memory");
  __syncthreads();

  // ---- A frag-major base: wave w owns frags f = 2w, 2w+1 of group g ----
  const char* Ab = (const char*)bi2f + (long)(g * 256 + 2 * w) * 1024 + l * 16;

  int C0[4];
  #pragma unroll
  for (int j = 0; j < 4; ++j) C0[j] = (j * 16 + x) * 16 + h;

  f32x4 accE[2][4] = {}, accO[2][4] = {};

  #pragma unroll
  for (int s = 0; s < 16; ++s){
    bf16x8 aE0 = *(const bf16x8*)(Ab + s * 8192);
    bf16x8 aE1 = *(const bf16x8*)(Ab + s * 8192 + 1024);
    bf16x8 aO0 = *(const bf16x8*)(Ab + 131072 + s * 8192);
    bf16x8 aO1 = *(const bf16x8*)(Ab + 131072 + s * 8192 + 1024);
    bf16x8 bqE[4], bqO[4];
    #pragma unroll
    for (int j = 0; j < 4; ++j){
      int C = C0[j] + s * 4; int ad = (C ^ ((C >> 4) & 15)) << 4;
      bqE[j] = *(const bf16x8*)(LDS + ad);
      bqO[j] = *(const bf16x8*)(LDS + EB64 + ad);
    }
    __builtin_amdgcn_s_setprio(1);
    #pragma unroll
    for (int j = 0; j < 4; ++j){
      accE[0][j] = __builtin_amdgcn_mfma_f32_16x16x32_bf16(aE0, bqE[j], accE[0][j], 0, 0, 0);
      accE[1][j] = __builtin_amdgcn_mfma_f32_16x16x32_bf16(aE1, bqE[j], accE[1][j], 0, 0, 0);
    }
    #pragma unroll
    for (int j = 0; j < 4; ++j){
      accO[0][j] = __builtin_amdgcn_mfma_f32_16x16x32_bf16(aO0, bqO[j], accO[0][j], 0, 0, 0);
      accO[1][j] = __builtin_amdgcn_mfma_f32_16x16x32_bf16(aO1, bqO[j], accO[1][j], 0, 0, 0);
    }
    __builtin_amdgcn_s_setprio(0);
  }

  // ---- transpose fill: u32 tile [64 tl][64 slots], slot ^= (tl&7)<<2 ----
  __syncthreads();   // all K-loop LDS reads done; safe to overwrite audio planes
  #pragma unroll
  for (int i = 0; i < 2; ++i){
    int cp1 = w * 8 + i * 4 + h;            // 0..31 -> c0 = g*64 + 2*cp1
    int sm  = 63 - cp1;                     // 32..63 -> p = 518-c0, 519-c0
    #pragma unroll
    for (int j = 0; j < 4; ++j){
      int tl = j * 16 + x;
      f32x4 E = accE[i][j], O = accO[i][j];
      float m1 = fsqrt_a((E[0]+O[0])*(E[0]+O[0]) + (E[1]+O[1])*(E[1]+O[1]));  // X[c0]
      float m2 = fsqrt_a((E[2]+O[2])*(E[2]+O[2]) + (E[3]+O[3])*(E[3]+O[3]));  // X[c0+1]
      float m3 = fsqrt_a((E[0]-O[0])*(E[0]-O[0]) + (E[1]-O[1])*(E[1]-O[1]));  // X[512-c0]
      float m4 = fsqrt_a((E[2]-O[2])*(E[2]-O[2]) + (E[3]-O[3])*(E[3]-O[3]));  // X[511-c0]
      unsigned p1 = (unsigned)f2bf(m1) | ((unsigned)f2bf(m2) << 16);
      unsigned p2 = (unsigned)f2bf(m4) | ((unsigned)f2bf(m3) << 16);
      int xs = (tl & 7) << 2;
      *(unsigned*)(LDS + tl * 256 + ((cp1 ^ xs) << 2)) = p1;
      *(unsigned*)(LDS + tl * 256 + ((sm  ^ xs) << 2)) = p2;
    }
  }
  __syncthreads();

  // ---- coalesced readout: 4 passes, 16B/thread; direct [64g,+64), mirror [456-64g,+64) ----
  {
    const long rowbase = (long)(nt64 * 64) * CPAD;
    int grp = tid & 15, rr = tid >> 4;      // 16 slot-groups x 16 rows
    int cb0 = (grp < 8) ? (g * 64 + grp * 8) : (456 - 64 * g + (grp - 8) * 8);
    #pragma unroll
    for (int pass = 0; pass < 4; ++pass){
      int tl = pass * 16 + rr;
      int f4 = (grp * 4) ^ ((tl & 7) << 2);
      i32x4 vv = *(const i32x4*)(LDS + tl * 256 + f4 * 4);
      *(i32x4*)((char*)magT + (rowbase + (long)tl * CPAD + cb0) * 2) = vv;
    }
  }
}

// ---------- k_mel: 512 blocks (64-wide t tiles), pair-line-swizzled LDS ----------
__launch_bounds__(256)
__global__ void k_mel(const unsigned short* __restrict__ wb,
                      const unsigned short* __restrict__ magT,
                      float* __restrict__ out){
  __shared__ unsigned short Ws[80 * 32];    // 5120 B, pair-line swizzle
  __shared__ unsigned short Ms[64 * 32];    // 4096 B, pair-line swizzle
  int tid = threadIdx.x, l = tid & 63, w = tid >> 6;
  int x = l & 15, h = l >> 4;
  int bx = blockIdx.x;
  int bt = bx & 15, b = bx >> 4;
  int t0 = bt * 64;
  f32x4 acc[5] = {};
  const char* Mb = (const char*)(magT + ((long)b * 1024 + t0) * CPAD);
  const char* Wb = (const char*)wb;

  for (int kt = 0; kt < 18; ++kt){
    int k0b = kt * 64;
    {
      int pl = tid >> 3, sl = (tid & 7) ^ (pl & 7);
      gload_lds16(Wb + (pl * 2 + (sl >> 2)) * 1152 + k0b + (sl & 3) * 16, (char*)Ws + tid * 16);
      if (w == 0){
        int d2 = 256 + l;
        int pl2 = d2 >> 3, sl2 = (d2 & 7) ^ (pl2 & 7);
        gload_lds16(Wb + (pl2 * 2 + (sl2 >> 2)) * 1152 + k0b + (sl2 & 3) * 16, (char*)Ws + d2 * 16);
      }
    }
    {
      int pl = tid >> 3, sl = (tid & 7) ^ (pl & 7);
      gload_lds16(Mb + (long)(pl * 2 + (sl >> 2)) * 1152 + k0b + (sl & 3) * 16, (char*)Ms + tid * 16);
    }
    __syncthreads();
    bf16x8 af[5], bfr;
    #pragma unroll
    for (int i = 0; i < 5; ++i){
      int row = i * 16 + x;
      int pl = row >> 1, sl = (((row & 1) << 2) + h) ^ (pl & 7);
      af[i] = *(const bf16x8*)((const char*)Ws + pl * 128 + sl * 16);
    }
    {
      int row = w * 16 + x;
      int pl = row >> 1, sl = (((row & 1) << 2) + h) ^ (pl & 7);
      bfr = *(const bf16x8*)((const char*)Ms + pl * 128 + sl * 16);
    }
    #pragma unroll
    for (int i = 0; i < 5; ++i)
      acc[i] = __builtin_amdgcn_mfma_f32_16x16x32_bf16(af[i], bfr, acc[i], 0, 0, 0);
    __syncthreads();
  }
  int t = t0 + w * 16 + x;
  #pragma unroll
  for (int i = 0; i < 5; ++i){
    int m = i * 16 + (h << 2);
    #pragma unroll
    for (int r = 0; r < 4; ++r)
      out[((long)b * NMELS + (m + r)) * 1024 + t] = flog_a(fmaxf(acc[i][r], 1e-5f));
  }
}

__global__ void k_sentinel(float* out, int n){
  int i = blockIdx.x * 256 + threadIdx.x;
  if (i < n) out[i] = 12345.0f;
}

extern "C" void kernel_launch(void* const* d_in, const int* in_sizes, int n_in,
                              void* d_out, int out_size, void* d_ws, size_t ws_size,
                              hipStream_t stream){
  const float* audio = (const float*)d_in[0];
  const float* basis = (const float*)d_in[1];
  const float* melw  = (const float*)d_in[2];
  float* out = (float*)d_out;

  size_t off_bi  = 0;                                            // bi2f: 1 MB
  size_t off_wb  = (size_t)1024 * 1024;
  size_t off_beo = off_wb + (size_t)NMELS * CPAD * 2;            // 4 KB f32 basisEO
  size_t off_mag = off_beo + 1024 * 4;
  size_t off_pl  = off_mag + (size_t)32 * 1024 * CPAD * 2;
  size_t total   = off_pl + (size_t)32 * 2 * PBYTES;             // ~55.7 MB

  if (ws_size < total){
    k_sentinel<<<(out_size + 255) / 256, 256, 0, stream>>>(out, out_size);
    return;
  }
  char* ws = (char*)d_ws;
  unsigned short* bi2f   = (unsigned short*)(ws + off_bi);
  unsigned short* wb     = (unsigned short*)(ws + off_wb);
  float*          beo    = (float*)(ws + off_beo);
  unsigned short* magT   = (unsigned short*)(ws + off_mag);
  unsigned short* planes = (unsigned short*)(ws + off_pl);

  k_audio_prep<<< 2520, 256, 0, stream>>>(audio, basis, melw, planes, bi2f, wb, beo);
  k_stft      <<<10240, 256, 0, stream>>>(bi2f, planes, beo, magT);
  k_mel       <<<  512, 256, 0, stream>>>(wb, magT, out);
}